// Round 1
// baseline (1346.522 us; speedup 1.0000x reference)
//
#include <hip/hip_runtime.h>

#define NN 50000
#define NE 1600000

using bf16x8 = __bf16 __attribute__((ext_vector_type(8)));
using f32x4  = float  __attribute__((ext_vector_type(4)));

__device__ __forceinline__ char* swzp(void* base, int row, int byteoff) {
  return (char*)base + (byteoff ^ ((row & 7) << 4));
}
__device__ __forceinline__ const char* swzpc(const void* base, int row, int byteoff) {
  return (const char*)base + (byteoff ^ ((row & 7) << 4));
}

// edge_index may be int32 (JAX default, x64 disabled) or int64. Runtime-detected flag.
__device__ __forceinline__ int ld_idx(const void* p, int f64, long long i) {
  return f64 ? (int)((const long long*)p)[i] : ((const int*)p)[i];
}

__global__ void detect_idx64(const int* ei32, int* flag) {
  __shared__ int anynz;
  if (threadIdx.x == 0) anynz = 0;
  __syncthreads();
  if (ei32[2 * threadIdx.x + 1] != 0) atomicOr(&anynz, 1);
  __syncthreads();
  if (threadIdx.x == 0) *flag = (anynz == 0) ? 1 : 0;
}

// Convert weights to bf16 scratch copies.
// wHUW [256n][256k] rows 0-127 = W_hu, 128-255 = W_hw
// wET2 [256n][256k] rows 0-127 = W_emb, 128-255 = W2
// wE [128][128], wA [128][128]
__global__ void prep_weights(const float* We, const float* Whu, const float* Whw,
                             const float* W2, const float* Wemb, const float* Wattr,
                             __bf16* wHUW, __bf16* wET2, __bf16* wE, __bf16* wA) {
  int i = blockIdx.x * 256 + threadIdx.x;
  if (i < 65536) {
    int n = i >> 8, k = i & 255;
    wHUW[i] = (__bf16)(n < 128 ? Whu[n * 256 + k] : Whw[(n - 128) * 256 + k]);
  } else if (i < 131072) {
    int j = i - 65536; int n = j >> 8, k = j & 255;
    wET2[j] = (__bf16)(n < 128 ? Wemb[n * 256 + k] : W2[(n - 128) * 256 + k]);
  } else if (i < 147456) {
    int j = i - 131072; wE[j] = (__bf16)We[j];
  } else {
    int j = i - 147456; wA[j] = (__bf16)Wattr[j];
  }
}

__global__ void count_edges(const void* ei, const int* flag, float* cnt) {
  int i = blockIdx.x * 256 + threadIdx.x;
  int f = *flag;
  int t = ld_idx(ei, f, (long long)NE + i);
  unsafeAtomicAdd(&cnt[t], 1.0f);
}

// C[M,256] = A[M,256] @ W[256,256]^T  (A f32 -> bf16 on the fly, W bf16 pre-staged)
// MODE 0: store bf16 hu (cols 0-127) / hw (cols 128-255)
// MODE 1: out = acc[emb] + lrelu(acc[t2] + sums/max(cnt,1))
template <int MODE>
__global__ __launch_bounds__(512) void node_gemm(
    const float* __restrict__ x, const __bf16* __restrict__ W,
    __bf16* __restrict__ hu, __bf16* __restrict__ hw,
    const float* __restrict__ sums, const float* __restrict__ cnt,
    float* __restrict__ out) {
  __shared__ __bf16 sW[256 * 256];  // 128 KB, XOR-swizzled
  const int t = threadIdx.x;
  const int lane = t & 63;
  const int w = t >> 6;  // 0..7

  for (int i = t; i < 8192; i += 512) {
    int row = i >> 5, c8 = (i & 31) << 3;
    bf16x8 v = *(const bf16x8*)(W + row * 256 + c8);
    *(bf16x8*)swzp(sW, row, row * 512 + (c8 << 1)) = v;
  }
  __syncthreads();

  const int ntiles = (NN + 127) / 128;  // 391
  for (int tile = blockIdx.x; tile < ntiles; tile += gridDim.x) {
    int m0 = tile * 128 + w * 16;
    int arow = m0 + (lane & 15);
    f32x4 acc[16];
#pragma unroll
    for (int n = 0; n < 16; ++n) { acc[n][0] = 0.f; acc[n][1] = 0.f; acc[n][2] = 0.f; acc[n][3] = 0.f; }
#pragma unroll
    for (int ks = 0; ks < 8; ++ks) {
      bf16x8 a;
      if (arow < NN) {
        const float* ap = x + (long long)arow * 256 + ks * 32 + ((lane >> 4) << 3);
        f32x4 fa = *(const f32x4*)ap;
        f32x4 fb = *(const f32x4*)(ap + 4);
#pragma unroll
        for (int j = 0; j < 4; ++j) { a[j] = (__bf16)fa[j]; a[j + 4] = (__bf16)fb[j]; }
      } else {
#pragma unroll
        for (int j = 0; j < 8; ++j) a[j] = (__bf16)0.f;
      }
#pragma unroll
      for (int n = 0; n < 16; ++n) {
        int row = n * 16 + (lane & 15);
        bf16x8 b = *(const bf16x8*)swzpc(sW, row, row * 512 + ks * 64 + ((lane >> 4) << 4));
        acc[n] = __builtin_amdgcn_mfma_f32_16x16x32_bf16(a, b, acc[n], 0, 0, 0);
      }
    }
    const int NOUT = (MODE == 0) ? 16 : 8;
#pragma unroll
    for (int n = 0; n < NOUT; ++n) {
      int col = n * 16 + (lane & 15);
#pragma unroll
      for (int j = 0; j < 4; ++j) {
        int row = m0 + ((lane >> 4) << 2) + j;
        if (row < NN) {
          if (MODE == 0) {
            float v = acc[n][j];
            if (col < 128) hu[(long long)row * 128 + col] = (__bf16)v;
            else           hw[(long long)row * 128 + (col - 128)] = (__bf16)v;
          } else {
            float c = cnt[row];
            float agg = sums[(long long)row * 128 + col] / fmaxf(c, 1.0f);
            float z = acc[n + 8][j] + agg;
            float lr = z >= 0.f ? z : 0.01f * z;
            out[(long long)row * 128 + col] = acc[n][j] + lr;
          }
        }
      }
    }
  }
}

// Fused edge pipeline: msg = lrelu(eattr@We^T + hu[src] + hw[tgt]);
// atomic scatter msg into sums; attributes = msg@Wattr^T.
__global__ __launch_bounds__(512) void edge_fused(
    const float* __restrict__ eattr, const void* __restrict__ ei, const int* __restrict__ flag,
    const __bf16* __restrict__ wE, const __bf16* __restrict__ wA,
    const __bf16* __restrict__ hu, const __bf16* __restrict__ hw,
    float* __restrict__ sums, float* __restrict__ attr_out) {
  __shared__ __bf16 sW1[128 * 128];   // We, swizzled
  __shared__ __bf16 sW2[128 * 128];   // Wattr, swizzled
  __shared__ __bf16 sHS[128 * 136];   // hu[src]+hw[tgt], padded pitch
  __shared__ __bf16 sMSG[128 * 128];  // msg bf16, swizzled
  __shared__ int sIdx[256];           // src[128], tgt[128]

  const int t = threadIdx.x;
  const int lane = t & 63;
  const int w = t >> 6;  // 0..7
  const int f = *flag;

  for (int i = t; i < 2048; i += 512) {
    int row = i >> 4, c8 = (i & 15) << 3;
    bf16x8 v1 = *(const bf16x8*)(wE + row * 128 + c8);
    bf16x8 v2 = *(const bf16x8*)(wA + row * 128 + c8);
    int b = row * 256 + (c8 << 1);
    *(bf16x8*)swzp(sW1, row, b) = v1;
    *(bf16x8*)swzp(sW2, row, b) = v2;
  }

  const int ntiles = NE / 128;  // 12500
  for (int tile = blockIdx.x; tile < ntiles; tile += gridDim.x) {
    __syncthreads();  // protects sIdx/sHS/sMSG from previous iteration readers
    int e0 = tile * 128;
    if (t < 128) {
      sIdx[t]       = ld_idx(ei, f, e0 + t);
      sIdx[128 + t] = ld_idx(ei, f, (long long)NE + e0 + t);
    }
    __syncthreads();
    for (int i = t; i < 2048; i += 512) {
      int r = i >> 4, c8 = (i & 15) << 3;
      bf16x8 a = *(const bf16x8*)(hu + (long long)sIdx[r] * 128 + c8);
      bf16x8 b = *(const bf16x8*)(hw + (long long)sIdx[128 + r] * 128 + c8);
      bf16x8 o;
#pragma unroll
      for (int j = 0; j < 8; ++j) o[j] = (__bf16)((float)a[j] + (float)b[j]);
      *(bf16x8*)(sHS + r * 136 + c8) = o;
    }
    __syncthreads();

    // GEMM1: wave w owns edges [e0+w*16, +16)
    const float* Abase = eattr + (long long)(e0 + w * 16 + (lane & 15)) * 128;
    f32x4 acc[8];
#pragma unroll
    for (int n = 0; n < 8; ++n) { acc[n][0] = 0.f; acc[n][1] = 0.f; acc[n][2] = 0.f; acc[n][3] = 0.f; }
#pragma unroll
    for (int ks = 0; ks < 4; ++ks) {
      f32x4 fa = *(const f32x4*)(Abase + ks * 32 + ((lane >> 4) << 3));
      f32x4 fb = *(const f32x4*)(Abase + ks * 32 + ((lane >> 4) << 3) + 4);
      bf16x8 a;
#pragma unroll
      for (int j = 0; j < 4; ++j) { a[j] = (__bf16)fa[j]; a[j + 4] = (__bf16)fb[j]; }
#pragma unroll
      for (int n = 0; n < 8; ++n) {
        int row = n * 16 + (lane & 15);
        bf16x8 b = *(const bf16x8*)swzpc(sW1, row, row * 256 + ks * 64 + ((lane >> 4) << 4));
        acc[n] = __builtin_amdgcn_mfma_f32_16x16x32_bf16(a, b, acc[n], 0, 0, 0);
      }
    }
    // epilogue 1: add gathered hs, lrelu, atomic scatter, msg->LDS (bf16, swizzled)
#pragma unroll
    for (int n = 0; n < 8; ++n) {
      int col = n * 16 + (lane & 15);
#pragma unroll
      for (int j = 0; j < 4; ++j) {
        int rloc = w * 16 + ((lane >> 4) << 2) + j;
        float z = acc[n][j] + (float)sHS[rloc * 136 + col];
        float m = z >= 0.f ? z : 0.01f * z;
        unsafeAtomicAdd(&sums[(long long)sIdx[128 + rloc] * 128 + col], m);
        *(__bf16*)swzp(sMSG, rloc, rloc * 256 + (col << 1)) = (__bf16)m;
      }
    }
    __syncthreads();

    // GEMM2: attributes = msg @ Wattr^T
    f32x4 acc2[8];
#pragma unroll
    for (int n = 0; n < 8; ++n) { acc2[n][0] = 0.f; acc2[n][1] = 0.f; acc2[n][2] = 0.f; acc2[n][3] = 0.f; }
    int rA = w * 16 + (lane & 15);
#pragma unroll
    for (int ks = 0; ks < 4; ++ks) {
      bf16x8 a = *(const bf16x8*)swzpc(sMSG, rA, rA * 256 + ks * 64 + ((lane >> 4) << 4));
#pragma unroll
      for (int n = 0; n < 8; ++n) {
        int row = n * 16 + (lane & 15);
        bf16x8 b = *(const bf16x8*)swzpc(sW2, row, row * 256 + ks * 64 + ((lane >> 4) << 4));
        acc2[n] = __builtin_amdgcn_mfma_f32_16x16x32_bf16(a, b, acc2[n], 0, 0, 0);
      }
    }
#pragma unroll
    for (int n = 0; n < 8; ++n) {
      int col = n * 16 + (lane & 15);
#pragma unroll
      for (int j = 0; j < 4; ++j) {
        int rloc = w * 16 + ((lane >> 4) << 2) + j;
        attr_out[(long long)(e0 + rloc) * 128 + col] = acc2[n][j];
      }
    }
  }
}

extern "C" void kernel_launch(void* const* d_in, const int* in_sizes, int n_in,
                              void* d_out, int out_size, void* d_ws, size_t ws_size,
                              hipStream_t stream) {
  const float* x     = (const float*)d_in[0];
  const void*  ei    = d_in[1];
  const float* eattr = (const float*)d_in[2];
  const float* We    = (const float*)d_in[3];
  const float* Whu   = (const float*)d_in[4];
  const float* Whw   = (const float*)d_in[5];
  const float* W2    = (const float*)d_in[6];
  const float* Wemb  = (const float*)d_in[7];
  const float* Wattr = (const float*)d_in[8];

  float* out_emb  = (float*)d_out;
  float* out_attr = out_emb + (size_t)NN * 128;

  char* ws = (char*)d_ws;
  float*  sums = (float*)ws;                          // 25,600,000 B
  float*  cnt  = (float*)(ws + 25600000);             //    200,000 B
  int*    flag = (int*)(ws + 25800000);
  __bf16* hu   = (__bf16*)(ws + 25800064);            // 12,800,000 B
  __bf16* hw   = (__bf16*)(ws + 25800064 + 12800000); // 12,800,000 B
  __bf16* wHUW = (__bf16*)(ws + 25800064 + 25600000); //    131,072 B
  __bf16* wET2 = wHUW + 65536;
  __bf16* wE   = wET2 + 65536;
  __bf16* wA   = wE + 16384;

  hipMemsetAsync(sums, 0, 25800000, stream);  // sums + cnt
  detect_idx64<<<1, 1024, 0, stream>>>((const int*)ei, flag);
  prep_weights<<<640, 256, 0, stream>>>(We, Whu, Whw, W2, Wemb, Wattr, wHUW, wET2, wE, wA);
  count_edges<<<6250, 256, 0, stream>>>(ei, flag, cnt);
  node_gemm<0><<<391, 512, 0, stream>>>(x, wHUW, hu, hw, nullptr, nullptr, nullptr);
  edge_fused<<<1024, 512, 0, stream>>>(eattr, ei, flag, wE, wA, hu, hw, sums, out_attr);
  node_gemm<1><<<391, 512, 0, stream>>>(x, wET2, nullptr, nullptr, sums, cnt, out_emb);
}